// Round 10
// baseline (686.909 us; speedup 1.0000x reference)
//
#include <hip/hip_runtime.h>
#include <hip/hip_bf16.h>

// ---------------------------------------------------------------------------
// GCN forward, 12-launch pipeline (gaps ~0 under graph capture, R9):
//   direct global-atomic CSR build: zero -> deg(atomic hist) -> scan1/scan2
//   -> fix(rowptr/cur/dis) -> scatter(atomic) -> pad
//   -> gemm1 (x@W1, MFMA) -> aggF(W2) -> aggF(W3) -> agg3 -> head.
// aggF = R2-structure gather aggregate + fused 16x64 @ 64x64 MFMA epilogue
// producing the NEXT layer's hs (dis-scaled bf16) directly.
// hs = dis[n]*h[n] bf16 [N+1][64] (+zero dummy row N).
// NOTE (R5): NO float LDS atomics. (R8): don't fuse gather INTO gemm tile.
// NOTE (R10/R11): k_agg not VALU- or issue-latency-bound.
// NOTE (R12/R13/R15): spatial slabs + per-tile chains lose; k_agg wall =
// dur ~= FETCH/3.5TB/s at 1 line-req/edge with full MLP.
// NOTE (R17): cooperative build FAILED (grid.sync x4 = 255us).
// NOTE (R19): R9 showed launch gaps ~0 (graph capture): removing 2 gemms
// saved only 5us. Budget audit: 5-kernel build ~180us = dominant cost.
// dst uniform over 100k counters -> global-atomic contention negligible ->
// direct 2-pass build replaces hierarchical sort (drops epart round-trip,
// one edge pass, 2 LDS-atomic stages). Tile-ordering dropped (was ~3%).
// ---------------------------------------------------------------------------

#define MAXNB 512       // max scan blocks (N <= 131072)

typedef __attribute__((ext_vector_type(8))) short short8;
typedef __attribute__((ext_vector_type(4))) float floatx4;
typedef __attribute__((ext_vector_type(2))) float f32x2;

__device__ __forceinline__ float bf2f(unsigned short v) {
    return __uint_as_float(((unsigned int)v) << 16);
}
__device__ __forceinline__ unsigned short f2bf(float x) {
    __hip_bfloat16 b = __float2bfloat16(x);
    return *(unsigned short*)&b;
}
__device__ __forceinline__ void pkacc(f32x2& a, unsigned int u) {
    f32x2 p;
    p.x = __uint_as_float(u << 16);
    p.y = __uint_as_float(u & 0xFFFF0000u);
    asm("v_pk_add_f32 %0, %1, %0" : "+v"(a) : "v"(p));
}
__device__ __forceinline__ void accp(f32x2* a, uint4 u) {
    pkacc(a[0], u.x);
    pkacc(a[1], u.y);
    pkacc(a[2], u.z);
    pkacc(a[3], u.w);
}

// B0: zero the degree array.
__global__ __launch_bounds__(256) void k_zero(int* __restrict__ deg, int N) {
    int i = blockIdx.x * 256 + threadIdx.x;
    if (i < N) deg[i] = 0;
}

// B1: global-atomic degree histogram (int4-vectorized dst reads).
__global__ __launch_bounds__(256) void k_deg(const int* __restrict__ dst,
                                             int* __restrict__ deg, int E) {
    int nv = E >> 2;
    const int4* d4 = (const int4*)dst;
    int stride = gridDim.x * 256;
    for (int i = blockIdx.x * 256 + threadIdx.x; i < nv; i += stride) {
        int4 v = d4[i];
        atomicAdd(&deg[v.x], 1);
        atomicAdd(&deg[v.y], 1);
        atomicAdd(&deg[v.z], 1);
        atomicAdd(&deg[v.w], 1);
    }
    for (int i = (nv << 2) + blockIdx.x * 256 + threadIdx.x; i < E; i += stride)
        atomicAdd(&deg[dst[i]], 1);
}

// B2a: per-256-node block exclusive scan of padded counts pcv=(deg+7)&~7.
// rowptr gets block-local exclusive prefix; btot[j] = block total.
__global__ __launch_bounds__(256) void k_scan1(const int* __restrict__ deg,
                                               int* __restrict__ rowptr,
                                               int* __restrict__ btot, int N) {
    __shared__ int sm[256];
    int j = blockIdx.x, t = threadIdx.x;
    int n = j * 256 + t;
    int pcv = (n < N) ? ((deg[n] + 7) & ~7) : 0;
    sm[t] = pcv;
    __syncthreads();
    for (int d = 1; d < 256; d <<= 1) {
        int u = (t >= d) ? sm[t - d] : 0;
        __syncthreads();
        sm[t] += u;
        __syncthreads();
    }
    if (n < N) rowptr[n] = sm[t] - pcv;
    if (t == 255) btot[j] = sm[255];
}

// B2b: single-block scan of block totals -> bstarts[0..nb]. Also zeroes the
// dummy hs rows (index N) of both ping-pong buffers.
__global__ __launch_bounds__(256) void k_scan2(const int* __restrict__ btot,
                                               int* __restrict__ bstarts, int nb,
                                               unsigned short* __restrict__ z1,
                                               unsigned short* __restrict__ z2,
                                               int N) {
    __shared__ int sm[256];
    int t = threadIdx.x;
    if (t < 64) {
        z1[(size_t)N * 64 + t] = 0;
        z2[(size_t)N * 64 + t] = 0;
    }
    int base = t * 2;
    int v0 = (base + 0 < nb) ? btot[base + 0] : 0;
    int v1 = (base + 1 < nb) ? btot[base + 1] : 0;
    int tsum = v0 + v1;
    sm[t] = tsum;
    __syncthreads();
    for (int d = 1; d < 256; d <<= 1) {
        int u = (t >= d) ? sm[t - d] : 0;
        __syncthreads();
        sm[t] += u;
        __syncthreads();
    }
    int excl = sm[t] - tsum;
    if (base + 0 < nb) bstarts[base + 0] = excl;
    if (base + 1 < nb) bstarts[base + 1] = excl + v0;
    if (t == 255) bstarts[nb] = sm[255];
}

// B3: finalize rowptr (+block start), init cur, compute dis.
__global__ __launch_bounds__(256) void k_fix(int* __restrict__ rowptr,
                                             int* __restrict__ cur,
                                             float* __restrict__ dis,
                                             const int* __restrict__ deg,
                                             const int* __restrict__ bstarts,
                                             int N) {
    int n = blockIdx.x * 256 + threadIdx.x;
    if (n < N) {
        int rp = rowptr[n] + bstarts[n >> 8];
        rowptr[n] = rp;
        cur[n] = rp;
        dis[n] = rsqrtf((float)deg[n] + 1.0f);
    }
}

// B4: global-atomic scatter: colidx[atomicAdd(cur[dst])] = src<<7 (byte off).
__global__ __launch_bounds__(256) void k_scatter(const int* __restrict__ src,
                                                 const int* __restrict__ dst,
                                                 int* __restrict__ cur,
                                                 int* __restrict__ colidx, int E) {
    int nv = E >> 2;
    const int4* d4 = (const int4*)dst;
    const int4* s4 = (const int4*)src;
    int stride = gridDim.x * 256;
    for (int i = blockIdx.x * 256 + threadIdx.x; i < nv; i += stride) {
        int4 d = d4[i];
        int4 s = s4[i];
        int p;
        p = atomicAdd(&cur[d.x], 1); colidx[p] = s.x << 7;
        p = atomicAdd(&cur[d.y], 1); colidx[p] = s.y << 7;
        p = atomicAdd(&cur[d.z], 1); colidx[p] = s.z << 7;
        p = atomicAdd(&cur[d.w], 1); colidx[p] = s.w << 7;
    }
    for (int i = (nv << 2) + blockIdx.x * 256 + threadIdx.x; i < E; i += stride) {
        int p = atomicAdd(&cur[dst[i]], 1);
        colidx[p] = src[i] << 7;
    }
}

// B5: pad each node's list to x8 with dummy row N.
__global__ __launch_bounds__(256) void k_pad(const int* __restrict__ rowptr,
                                             const int* __restrict__ deg,
                                             int* __restrict__ colidx, int N) {
    int n = blockIdx.x * 256 + threadIdx.x;
    if (n < N) {
        int c = deg[n];
        int q = rowptr[n] + c;
        int endp = rowptr[n] + ((c + 7) & ~7);
        int dv = N << 7;
        for (; q < endp; ++q) colidx[q] = dv;
    }
}

// ---------------- layer-1 GEMM (fp32 A, K=128) ----------------
template <int K, int ABF16>
__global__ __launch_bounds__(256) void k_gemm_mfma(const void* __restrict__ Ap,
                                                   const float* __restrict__ W,
                                                   const float* __restrict__ dis,
                                                   unsigned short* __restrict__ hs,
                                                   int N) {
    constexpr int AS = K + 8;
    __shared__ unsigned short As[64 * AS];
    __shared__ unsigned short Bt[64 * AS];
    const int tid = threadIdx.x;
    const int r0 = blockIdx.x * 64;

    for (int idx = tid; idx < K * 64; idx += 256) {
        int k = idx >> 6, n = idx & 63;
        Bt[n * AS + k] = f2bf(W[idx]);
    }
    if (ABF16) {
        const unsigned short* A = (const unsigned short*)Ap;
        for (int idx = tid; idx < 64 * (K / 8); idx += 256) {
            int row = idx / (K / 8), c8 = idx % (K / 8);
            int gr = r0 + row;
            uint4 v = (gr < N) ? *(const uint4*)&A[(size_t)gr * K + c8 * 8]
                               : make_uint4(0u, 0u, 0u, 0u);
            *(uint4*)&As[row * AS + c8 * 8] = v;
        }
    } else {
        const float* A = (const float*)Ap;
        for (int idx = tid; idx < 64 * (K / 4); idx += 256) {
            int row = idx / (K / 4), kq = idx % (K / 4);
            int gr = r0 + row;
            float4 a = (gr < N) ? ((const float4*)(A + (size_t)gr * K))[kq]
                                : make_float4(0.f, 0.f, 0.f, 0.f);
            ushort4 v;
            v.x = f2bf(a.x); v.y = f2bf(a.y); v.z = f2bf(a.z); v.w = f2bf(a.w);
            *(ushort4*)&As[row * AS + kq * 4] = v;
        }
    }
    __syncthreads();

    const int w = tid >> 6, lane = tid & 63;
    const int m = lane & 15, quad = lane >> 4;
    floatx4 acc0 = {0.f, 0.f, 0.f, 0.f};
    floatx4 acc1 = {0.f, 0.f, 0.f, 0.f};
    floatx4 acc2 = {0.f, 0.f, 0.f, 0.f};
    floatx4 acc3 = {0.f, 0.f, 0.f, 0.f};
#pragma unroll
    for (int s = 0; s < K / 32; ++s) {
        int ko = s * 32 + quad * 8;
        short8 a  = *(const short8*)&As[(w * 16 + m) * AS + ko];
        short8 b0 = *(const short8*)&Bt[(0 * 16 + m) * AS + ko];
        short8 b1 = *(const short8*)&Bt[(1 * 16 + m) * AS + ko];
        short8 b2 = *(const short8*)&Bt[(2 * 16 + m) * AS + ko];
        short8 b3 = *(const short8*)&Bt[(3 * 16 + m) * AS + ko];
        acc0 = __builtin_amdgcn_mfma_f32_16x16x32_bf16(a, b0, acc0, 0, 0, 0);
        acc1 = __builtin_amdgcn_mfma_f32_16x16x32_bf16(a, b1, acc1, 0, 0, 0);
        acc2 = __builtin_amdgcn_mfma_f32_16x16x32_bf16(a, b2, acc2, 0, 0, 0);
        acc3 = __builtin_amdgcn_mfma_f32_16x16x32_bf16(a, b3, acc3, 0, 0, 0);
    }
#pragma unroll
    for (int r = 0; r < 4; ++r) {
        int gr = r0 + w * 16 + quad * 4 + r;
        if (gr < N) {
            float dn = dis[gr];
            size_t base = (size_t)gr * 64 + m;
            hs[base + 0]  = f2bf(acc0[r] * dn);
            hs[base + 16] = f2bf(acc1[r] * dn);
            hs[base + 32] = f2bf(acc2[r] * dn);
            hs[base + 48] = f2bf(acc3[r] * dn);
        }
    }
}

// ---------------- gather aggregate (+ optional fused next-layer GEMM) ------
// R2 structure: 4 nodes/wave, lane = slot(2b) x eslot-parity(1b) x cq(3b),
// 2-deep pipeline, 1-level butterfly. FUSE: stage 16x64 bf16 out-tile in
// LDS, compute hs_next = dis * (out @ Wn) via 2x 16x16x32 MFMA per wave.
template <int RELU, int FUSE>
__global__ __launch_bounds__(256) void k_agg(const unsigned short* __restrict__ hs,
                                             const int* __restrict__ rowptr,
                                             const int* __restrict__ deg,
                                             const int* __restrict__ colidx,
                                             const float* __restrict__ dis,
                                             const float* __restrict__ bias,
                                             const float* __restrict__ Wn,
                                             unsigned short* __restrict__ outp,
                                             int N) {
    constexpr int WS = 72;
    __shared__ unsigned short Wt[FUSE ? 64 * WS : 1];
    __shared__ unsigned short Aout[FUSE ? 16 * WS : 1];

    int lane = threadIdx.x & 63;
    int wv = threadIdx.x >> 6;
    int s = lane >> 4;          // node slot 0..3
    int e = (lane >> 3) & 1;    // edge-slot parity
    int cq = lane & 7;          // channel octet
    int node = blockIdx.x * 16 + wv * 4 + s;
    bool valid = node < N;
    int nodec = valid ? node : 0;

    if (FUSE) {
        for (int idx = threadIdx.x; idx < 64 * 64; idx += 256) {
            int k = idx >> 6, c = idx & 63;
            Wt[c * WS + k] = f2bf(Wn[idx]);
        }
        // visibility via the __syncthreads before the matmul
    }

    int rp = rowptr[nodec];
    int cnt = valid ? deg[nodec] : 0;
    int pcnt = (cnt + 7) & ~7;
    int wm = pcnt;
    wm = max(wm, __shfl_xor(wm, 16, 64));
    wm = max(wm, __shfl_xor(wm, 32, 64));

    const int* ci = colidx + rp + e;
    const char* hb = (const char*)hs + cq * 16;
    const int DUMMY = N << 7;
    const int mclamp = max(pcnt - 2, 0);

    f32x2 acc[4];
    acc[0] = (f32x2){0.f, 0.f};
    acc[1] = (f32x2){0.f, 0.f};
    acc[2] = (f32x2){0.f, 0.f};
    acc[3] = (f32x2){0.f, 0.f};

    auto LDO = [&](int i, int& o0, int& o1) {
        int r0 = ci[min(i, mclamp)];
        int r1 = ci[min(i + 2, mclamp)];
        o0 = (i + e < pcnt) ? r0 : DUMMY;
        o1 = (i + 2 + e < pcnt) ? r1 : DUMMY;
    };

    if (wm > 0) {
        int a0, a1, b0, b1;
        LDO(0, a0, a1);
        LDO(4, b0, b1);
        uint4 gA0 = *(const uint4*)(hb + a0);
        uint4 gA1 = *(const uint4*)(hb + a1);
        uint4 gB0 = *(const uint4*)(hb + b0);
        uint4 gB1 = *(const uint4*)(hb + b1);
        for (int i = 8; i < wm; i += 8) {
            int c0, c1, d0, d1;
            LDO(i, c0, c1);
            LDO(i + 4, d0, d1);
            accp(acc, gA0);
            accp(acc, gA1);
            gA0 = *(const uint4*)(hb + c0);
            gA1 = *(const uint4*)(hb + c1);
            accp(acc, gB0);
            accp(acc, gB1);
            gB0 = *(const uint4*)(hb + d0);
            gB1 = *(const uint4*)(hb + d1);
        }
        accp(acc, gA0);
        accp(acc, gA1);
        accp(acc, gB0);
        accp(acc, gB1);
    }

#pragma unroll
    for (int q = 0; q < 4; ++q) {
        f32x2 t;
        t.x = __shfl_xor(acc[q].x, 8, 64);
        t.y = __shfl_xor(acc[q].y, 8, 64);
        asm("v_pk_add_f32 %0, %1, %0" : "+v"(acc[q]) : "v"(t));
    }

    uint4 ov = make_uint4(0u, 0u, 0u, 0u);
    if (e == 0 && valid) {
        uint4 sv = *(const uint4*)(hb + ((size_t)node << 7));
        accp(acc, sv);  // self-loop row (hs = dis*h)
        float dn = dis[node];
        float4 blo = *(const float4*)&bias[cq * 8];
        float4 bhi = *(const float4*)&bias[cq * 8 + 4];
        float bb[8] = {blo.x, blo.y, blo.z, blo.w, bhi.x, bhi.y, bhi.z, bhi.w};
        unsigned short o[8];
#pragma unroll
        for (int q = 0; q < 4; ++q) {
            float v0 = dn * acc[q].x + bb[2 * q + 0];
            float v1 = dn * acc[q].y + bb[2 * q + 1];
            if (RELU) {
                v0 = fmaxf(v0, 0.f);
                v1 = fmaxf(v1, 0.f);
            }
            o[2 * q + 0] = f2bf(v0);
            o[2 * q + 1] = f2bf(v1);
        }
        ov.x = (unsigned int)o[0] | ((unsigned int)o[1] << 16);
        ov.y = (unsigned int)o[2] | ((unsigned int)o[3] << 16);
        ov.z = (unsigned int)o[4] | ((unsigned int)o[5] << 16);
        ov.w = (unsigned int)o[6] | ((unsigned int)o[7] << 16);
    }

    if (FUSE) {
        if (e == 0) {
            *(uint4*)&Aout[(wv * 4 + s) * WS + cq * 8] = ov;  // zeros if !valid
        }
        __syncthreads();
        // 16x64(out) @ 64x64(Wn): wave wv computes cols [wv*16, wv*16+16)
        const int m = lane & 15, quad = lane >> 4;
        floatx4 cacc = {0.f, 0.f, 0.f, 0.f};
#pragma unroll
        for (int s2 = 0; s2 < 2; ++s2) {
            int ko = s2 * 32 + quad * 8;
            short8 a = *(const short8*)&Aout[m * WS + ko];
            short8 bf = *(const short8*)&Wt[(wv * 16 + m) * WS + ko];
            cacc = __builtin_amdgcn_mfma_f32_16x16x32_bf16(a, bf, cacc, 0, 0, 0);
        }
        int nb0 = blockIdx.x * 16;
#pragma unroll
        for (int r = 0; r < 4; ++r) {
            int nd = nb0 + quad * 4 + r;
            if (nd < N) {
                outp[(size_t)nd * 64 + wv * 16 + m] = f2bf(cacc[r] * dis[nd]);
            }
        }
    } else {
        if (e == 0 && valid) {
            *(uint4*)&outp[(size_t)node * 64 + cq * 8] = ov;
        }
    }
}

// ---------------- fused mean-pool + FC head ----------------
__global__ __launch_bounds__(256) void k_head2(const unsigned short* __restrict__ h,
                                               const int* __restrict__ batch,
                                               const float* __restrict__ Wfc,
                                               const float* __restrict__ bfc,
                                               float* __restrict__ out, int N) {
    __shared__ float part[4][64];
    __shared__ float p[64];
    int g = blockIdx.x, t = threadIdx.x;
    int w = t >> 6, lane = t & 63;
    int lo = 0, hi = N;
    while (lo < hi) { int mid = (lo + hi) >> 1; if (batch[mid] < g) lo = mid + 1; else hi = mid; }
    int s = lo;
    hi = N;
    while (lo < hi) { int mid = (lo + hi) >> 1; if (batch[mid] < g + 1) lo = mid + 1; else hi = mid; }
    int e = lo;
    float acc = 0.f;
    int n = s + w;
    for (; n + 12 < e; n += 16) {
        float a0 = bf2f(h[(size_t)(n + 0) * 64 + lane]);
        float a1 = bf2f(h[(size_t)(n + 4) * 64 + lane]);
        float a2 = bf2f(h[(size_t)(n + 8) * 64 + lane]);
        float a3 = bf2f(h[(size_t)(n + 12) * 64 + lane]);
        acc += (a0 + a1) + (a2 + a3);
    }
    for (; n < e; n += 4) acc += bf2f(h[(size_t)n * 64 + lane]);
    part[w][lane] = acc;
    __syncthreads();
    if (w == 0) {
        float a = (part[0][lane] + part[1][lane]) + (part[2][lane] + part[3][lane]);
        float cntf = (float)max(e - s, 1);
        p[lane] = a / cntf;
    }
    __syncthreads();
    if (t < 10) {
        float o = bfc[t];
#pragma unroll
        for (int hh = 0; hh < 64; ++hh) o += p[hh] * Wfc[hh * 10 + t];
        out[g * 10 + t] = o;
    }
}

extern "C" void kernel_launch(void* const* d_in, const int* in_sizes, int n_in,
                              void* d_out, int out_size, void* d_ws, size_t ws_size,
                              hipStream_t stream) {
    const float* x = (const float*)d_in[0];
    const int* eidx = (const int*)d_in[1];
    const int* batch = (const int*)d_in[2];
    const float* W1 = (const float*)d_in[3];
    const float* b1 = (const float*)d_in[4];
    const float* W2 = (const float*)d_in[5];
    const float* b2 = (const float*)d_in[6];
    const float* W3 = (const float*)d_in[7];
    const float* b3 = (const float*)d_in[8];
    const float* Wfc = (const float*)d_in[9];
    const float* bfc = (const float*)d_in[10];
    float* out = (float*)d_out;

    const int N = in_sizes[0] / 128;  // 100000
    const int E = in_sizes[1] / 2;    // 3200000
    const int G = out_size / 10;      // 512
    const int NBN = (N + 255) / 256;  // 391 node blocks

    char* ws = (char*)d_ws;
    size_t off = 0;
    auto alloc = [&](size_t bytes) -> char* {
        char* p = ws + off;
        off = (off + bytes + 511) & ~(size_t)511;
        return p;
    };
    int* deg = (int*)alloc((size_t)N * 4);
    int* rowptr = (int*)alloc((size_t)N * 4);
    int* cur = (int*)alloc((size_t)N * 4);
    float* dis = (float*)alloc((size_t)N * 4);
    int* btot = (int*)alloc((size_t)MAXNB * 4);
    int* bstarts = (int*)alloc((size_t)(MAXNB + 1) * 4);
    int* colidx = (int*)alloc(((size_t)E + (size_t)N * 8) * 4);
    unsigned short* hsA = (unsigned short*)alloc((size_t)(N + 1) * 64 * 2);
    unsigned short* hsB = (unsigned short*)alloc((size_t)(N + 1) * 64 * 2);
    unsigned short* obufb = (unsigned short*)alloc((size_t)N * 64 * 2);

    const int* esrc = eidx;
    const int* edst = eidx + E;

    // ---- direct global-atomic CSR build ----
    k_zero<<<NBN, 256, 0, stream>>>(deg, N);
    k_deg<<<1024, 256, 0, stream>>>(edst, deg, E);
    k_scan1<<<NBN, 256, 0, stream>>>(deg, rowptr, btot, N);
    k_scan2<<<1, 256, 0, stream>>>(btot, bstarts, NBN, hsA, hsB, N);
    k_fix<<<NBN, 256, 0, stream>>>(rowptr, cur, dis, deg, bstarts, N);
    k_scatter<<<1024, 256, 0, stream>>>(esrc, edst, cur, colidx, E);
    k_pad<<<NBN, 256, 0, stream>>>(rowptr, deg, colidx, N);

    int gblk = (N + 63) / 64;
    int ablk = (N + 15) / 16;
    k_gemm_mfma<128, 0><<<gblk, 256, 0, stream>>>(x, W1, dis, hsA, N);
    k_agg<1, 1><<<ablk, 256, 0, stream>>>(hsA, rowptr, deg, colidx, dis, b1, W2, hsB, N);
    k_agg<1, 1><<<ablk, 256, 0, stream>>>(hsB, rowptr, deg, colidx, dis, b2, W3, hsA, N);
    k_agg<0, 0><<<ablk, 256, 0, stream>>>(hsA, rowptr, deg, colidx, dis, b3, nullptr, obufb, N);
    k_head2<<<G, 256, 0, stream>>>(obufb, batch, Wfc, bfc, out, N);
}